// Round 13
// baseline (482.406 us; speedup 1.0000x reference)
//
#include <hip/hip_runtime.h>
#include <hip/hip_bf16.h>
#include <stdint.h>

typedef __hip_bfloat16 bf16;
typedef __attribute__((ext_vector_type(8))) short short8;
typedef __attribute__((ext_vector_type(4))) float f32x4;

#define SCALE_ 0.08838834764831845f  // 1/sqrt(128)

static __device__ __forceinline__ float bf2f(short u) {
  unsigned int x = ((unsigned int)(unsigned short)u) << 16;
  return __builtin_bit_cast(float, x);
}
static __device__ __forceinline__ short f2bf(float f) {
  __hip_bfloat16 h = __float2bfloat16(f);
  return __builtin_bit_cast(short, h);
}
static __device__ __forceinline__ f32x4 mfma16(short8 a, short8 b, f32x4 c) {
  return __builtin_amdgcn_mfma_f32_16x16x32_bf16(a, b, c, 0, 0, 0);
}
static __device__ __forceinline__ void gl_lds16(const bf16* g, bf16* l) {
  __builtin_amdgcn_global_load_lds(
      (const __attribute__((address_space(1))) unsigned int*)g,
      (__attribute__((address_space(3))) unsigned int*)l, 16, 0, 0);
}

// ---------------------------------------------------------------------------
// f32 -> bf16 conversion for x, wq, wk, wv, wo, prompt (one fused launch).
// ---------------------------------------------------------------------------
__global__ __launch_bounds__(256) void cvt6(
    const float* __restrict__ sx, const float* __restrict__ sq,
    const float* __restrict__ sk, const float* __restrict__ sv,
    const float* __restrict__ so, const float* __restrict__ sp,
    bf16* __restrict__ dx, bf16* __restrict__ dq, bf16* __restrict__ dk,
    bf16* __restrict__ dv, bf16* __restrict__ d4, bf16* __restrict__ dp)
{
  int b = blockIdx.x;
  const float* s; bf16* d; int off;
  if (b < 4096)       { s = sx; d = dx; off = b; }
  else if (b < 12288) { s = sq; d = dq; off = b - 4096; }
  else if (b < 20480) { s = sk; d = dk; off = b - 12288; }
  else if (b < 28672) { s = sv; d = dv; off = b - 20480; }
  else if (b < 36864) { s = so; d = d4; off = b - 28672; }
  else                { s = sp; d = dp; off = b - 36864; }
  long base = (long)off * 2048 + threadIdx.x * 8;
  f32x4 a = *(const f32x4*)(s + base);
  f32x4 c = *(const f32x4*)(s + base + 4);
  short8 o;
#pragma unroll
  for (int j = 0; j < 4; j++) { o[j] = f2bf(a[j]); o[4 + j] = f2bf(c[j]); }
  *(short8*)(d + base) = o;
}

// ---------------------------------------------------------------------------
// QKV GEMM v2 — hoisted-read 8-phase schedule (true m201 template form).
// 256x256 tile, BK=64, 8 waves (2m x 4n), 8 LDS slots x 16KB, DEPTH-6.
// Phase p: {stage(unit p+6); [vmcnt(8) @p1/p3]; ds_read frags for phase p+1
// into the ALTERNATE register set; s_waitcnt lgkmcnt(4|8) certifying phase
// p-1's reads (pre-barrier: closes WAR before any later stage can land);
// s_barrier; setprio MFMA (operands read at p-1)}.
// Sets: p0 MFMA(afA,bfA) reads afB<-A0.hi | p1 MFMA(afB,bfA) reads afA<-A1.lo
// + bfB<-B1 | p2 MFMA(afA,bfB) reads afB<-A1.hi | p3 MFMA(afB,bfB) reads
// afA<-A0'(t+1).lo + bfA<-B0'. Register WAR: read-target set never equals
// MFMA-operand set in the same phase (strict alternation).
// Certify-before-restage invariant (per unit type): A0 reads end p0, cert
// pre-bar p1, slot restaged p2; B0: end p3(t-1), cert p0, restage p3;
// A1: end p2, cert p3, restage p0(t+1); B1: end p1, cert p2, restage p1(t+1).
// vmcnt(8)@p1 certifies units <= 4t+3 (F2: a1,b1); @p3 certifies <= 4t+5
// (next tile's a0,b0). Tail drains 8 -> 4 -> 0. Drift <=1 phase (1 bar/phase).
// Math/order identical to round-12 -> absmax must be unchanged.
// ---------------------------------------------------------------------------
__global__ __launch_bounds__(512, 2) void gemm_bt(
    const bf16* __restrict__ A, const bf16* __restrict__ A2,
    const bf16* __restrict__ B0, const bf16* __restrict__ B1, const bf16* __restrict__ B2w,
    bf16* __restrict__ C0, bf16* __restrict__ C1, bf16* __restrict__ C2,
    bf16* __restrict__ P1, bf16* __restrict__ P2,
    int M1, int Mtot)
{
  __shared__ char lds[131072];   // 8 slots x 16KB
  const int tid = threadIdx.x, w = tid >> 6, l = tid & 63;
  const int lr = l & 15, lg = l >> 4;
  const int wm = w >> 2, wn = w & 3;
  const int z = blockIdx.z;
  const bf16* Bw = (z == 0) ? B0 : ((z == 1) ? B1 : B2w);
  bf16* C  = (z == 0) ? C0 : ((z == 1) ? C1 : C2);
  bf16* Cp = (z == 0) ? (bf16*)0 : ((z == 1) ? P1 : P2);

  const int cpx = gridDim.x >> 3, orig = blockIdx.x;
  const int wg = (orig & 7) * cpx + (orig >> 3);
  const long m0 = (long)(wg >> 4) * 256;
  const long n0 = (long)(wg & 15) * 256;

  const int r0 = ((tid >> 3) << 1) | ((tid >> 2) & 1);
  const int c0 = (tid & 3) ^ ((tid >> 3) & 3);
  const bf16 *pa0, *pa1;
  {
    long mx = (long)(Mtot - M1) - 1;
    long g0 = m0 + r0, g1 = m0 + r0 + 128;
    const bf16 *q0, *q1;
    if (g0 < M1) q0 = A + g0 * 4096;
    else { long rr = g0 - M1; if (rr > mx) rr = mx; q0 = A2 + rr * 4096; }
    if (g1 < M1) q1 = A + g1 * 4096;
    else { long rr = g1 - M1; if (rr > mx) rr = mx; q1 = A2 + rr * 4096; }
    pa0 = q0 + c0 * 8;
    pa1 = q1 + c0 * 8;
  }
  const bf16* pb0 = Bw + (n0 + r0) * 4096 + c0 * 8;
  const bf16* pb1 = pb0 + (long)128 * 4096;

  const int ro  = (lr >> 1) * 128 + (((lr & 1) * 4) + (lg ^ ((lr >> 1) & 3))) * 16;
  const int aro = wm * 8192 + ro;
  const int bro = wn * 4096 + ro;

  f32x4 acc[8][4];
#pragma unroll
  for (int i = 0; i < 8; i++)
#pragma unroll
    for (int j = 0; j < 4; j++) acc[i][j] = (f32x4){0.f, 0.f, 0.f, 0.f};

  short8 afA[4], afB[4], bfA[4], bfB[4];

#define SGA(BASE_, KE_)                                                      \
  {                                                                          \
    bf16* d_ = (bf16*)(lds + (BASE_)) + tid * 8;                             \
    gl_lds16(pa0 + (KE_), d_);                                               \
    gl_lds16(pa1 + (KE_), d_ + 4096);                                        \
  }
#define SGB(BASE_, KE_)                                                      \
  {                                                                          \
    bf16* d_ = (bf16*)(lds + (BASE_)) + tid * 8;                             \
    gl_lds16(pb0 + (KE_), d_);                                               \
    gl_lds16(pb1 + (KE_), d_ + 4096);                                        \
  }
#define RDA(SET_, BASE_, MO_)                                                \
  _Pragma("unroll") for (int mi = 0; mi < 4; mi++)                           \
    SET_[mi] = *(const short8*)(lds + (BASE_) + aro + ((MO_) + mi) * 1024);
#define RDB(SET_, BASE_)                                                     \
  _Pragma("unroll") for (int ni = 0; ni < 4; ni++)                           \
    SET_[ni] = *(const short8*)(lds + (BASE_) + bro + ni * 1024);
#define VMC(N_) asm volatile("s_waitcnt vmcnt(" N_ ")" ::: "memory");
#define WAITK(N_)                                                            \
  asm volatile("s_waitcnt lgkmcnt(" N_ ")" ::: "memory");                    \
  __builtin_amdgcn_sched_barrier(0);                                         \
  __builtin_amdgcn_s_barrier();                                              \
  __builtin_amdgcn_sched_barrier(0);
#define MM(AF_, BF_, MO_)                                                    \
  __builtin_amdgcn_s_setprio(1);                                             \
  _Pragma("unroll") for (int mi = 0; mi < 4; mi++)                           \
    _Pragma("unroll") for (int ni = 0; ni < 4; ni++)                         \
      acc[(MO_) + mi][ni] = mfma16(AF_[mi], BF_[ni], acc[(MO_) + mi][ni]);   \
  __builtin_amdgcn_s_setprio(0);

  // prologue: units 0..5 (tile0 A0,B0,A1,B1 + tile1 A0,B0), certify 0/1,
  // read F0(0) into set A.
  SGA(0, 0) SGB(16384, 0) SGA(32768, 32) SGB(49152, 32)
  SGA(65536, 64) SGB(65536 + 16384, 64)
  VMC("8")
  __builtin_amdgcn_s_barrier();
  __builtin_amdgcn_sched_barrier(0);
  RDA(afA, 0, 0) RDB(bfA, 16384)

  for (int t = 0; t < 62; t += 2) {
    const int ka = (t + 1) * 64 + 32, kb = (t + 2) * 64;
    const int kc = (t + 2) * 64 + 32, kd = (t + 3) * 64;
    // tile t (parity 0)
    SGA(65536 + 32768, ka) RDA(afB, 0, 4)                              WAITK("4") MM(afA, bfA, 0)
    SGB(65536 + 49152, ka) VMC("8") RDA(afA, 32768, 0) RDB(bfB, 49152) WAITK("8") MM(afB, bfA, 4)
    SGA(0, kb)             RDA(afB, 32768, 4)                          WAITK("4") MM(afA, bfB, 0)
    SGB(16384, kb)         VMC("8") RDA(afA, 65536, 0) RDB(bfA, 65536 + 16384) WAITK("8") MM(afB, bfB, 4)
    // tile t+1 (parity 1)
    SGA(32768, kc)         RDA(afB, 65536, 4)                          WAITK("4") MM(afA, bfA, 0)
    SGB(49152, kc)         VMC("8") RDA(afA, 65536 + 32768, 0) RDB(bfB, 65536 + 49152) WAITK("8") MM(afB, bfA, 4)
    SGA(65536, kd)         RDA(afB, 65536 + 32768, 4)                  WAITK("4") MM(afA, bfB, 0)
    SGB(65536 + 16384, kd) VMC("8") RDA(afA, 0, 0) RDB(bfA, 16384)     WAITK("8") MM(afB, bfB, 4)
  }
  // tile 62 (parity 0): stage only A1/B1 of tile 63 (KE = 63*64+32 = 4064)
  SGA(65536 + 32768, 4064) RDA(afB, 0, 4)                              WAITK("4") MM(afA, bfA, 0)
  SGB(65536 + 49152, 4064) VMC("8") RDA(afA, 32768, 0) RDB(bfB, 49152) WAITK("8") MM(afB, bfA, 4)
  RDA(afB, 32768, 4)                                                   WAITK("4") MM(afA, bfB, 0)
  VMC("4") RDA(afA, 65536, 0) RDB(bfA, 65536 + 16384)                  WAITK("8") MM(afB, bfB, 4)
  // tile 63 (parity 1): drain
  RDA(afB, 65536, 4)                                                   WAITK("4") MM(afA, bfA, 0)
  VMC("0") RDA(afA, 65536 + 32768, 0) RDB(bfB, 65536 + 49152)          WAITK("8") MM(afB, bfA, 4)
  RDA(afB, 65536 + 32768, 4)                                           WAITK("4") MM(afA, bfB, 0)
  WAITK("0") MM(afB, bfB, 4)

#undef MM
#undef WAITK
#undef VMC
#undef RDB
#undef RDA
#undef SGB
#undef SGA

  // epilogue: C/D layout col=lane&15, row=(lane>>4)*4+j
#pragma unroll
  for (int mi = 0; mi < 8; mi++) {
#pragma unroll
    for (int ni = 0; ni < 4; ni++) {
      long col = n0 + wn * 64 + ni * 16 + lr;
      f32x4 v = acc[mi][ni];
#pragma unroll
      for (int j = 0; j < 4; j++) {
        long row = m0 + wm * 128 + mi * 16 + lg * 4 + j;
        if (row < M1) {
          *(short*)(C + row * 4096 + col) = f2bf(v[j]);
        } else if (Cp != 0 && row < Mtot) {
          *(short*)(Cp + (row - M1) * 4096 + col) = f2bf(v[j]);
        }
      }
    }
  }
}

// ---------------------------------------------------------------------------
// Out-projection GEMM (round-9/10/12 verified, unchanged): 256x128, 256 blocks.
// ---------------------------------------------------------------------------
__global__ __launch_bounds__(512, 2) void gemm_n128(
    const bf16* __restrict__ A, const bf16* __restrict__ Bw,
    float* __restrict__ CF)
{
  __shared__ char lds[98304];
  const int tid = threadIdx.x, w = tid >> 6, l = tid & 63;
  const int lr = l & 15, lg = l >> 4;
  const int wm = w >> 1, wn = w & 1;

  const int cpx = gridDim.x >> 3, orig = blockIdx.x;
  const int wg = (orig & 7) * cpx + (orig >> 3);
  const long m0 = (long)(wg >> 5) * 256;
  const long n0 = (long)(wg & 31) * 128;

  const int r0 = ((tid >> 3) << 1) | ((tid >> 2) & 1);
  const int c0 = (tid & 3) ^ ((tid >> 3) & 3);
  const bf16* pa0 = A + (m0 + r0) * 4096 + c0 * 8;
  const bf16* pa1 = pa0 + (long)128 * 4096;
  const bf16* pb0 = Bw + (n0 + r0) * 4096 + c0 * 8;

  const int ro  = (lr >> 1) * 128 + (((lr & 1) * 4) + (lg ^ ((lr >> 1) & 3))) * 16;
  const int aro = wm * 4096 + ro;
  const int bro = wn * 4096 + ro;

  f32x4 acc[4][4];
#pragma unroll
  for (int i = 0; i < 4; i++)
#pragma unroll
    for (int j = 0; j < 4; j++) acc[i][j] = (f32x4){0.f, 0.f, 0.f, 0.f};

  short8 af[4], bf[4];

#define NSTGA(SB_, KE_)                                                      \
  {                                                                          \
    bf16* d_ = (bf16*)(lds + (SB_)) + tid * 8;                               \
    gl_lds16(pa0 + (KE_), d_);                                               \
    gl_lds16(pa1 + (KE_), d_ + 4096);                                        \
  }
#define NSTGB(SB_, KE_)                                                      \
  {                                                                          \
    bf16* d_ = (bf16*)(lds + (SB_)) + tid * 8;                               \
    gl_lds16(pb0 + (KE_), d_);                                               \
  }
#define NSYNC(VM_)                                                           \
  {                                                                          \
    asm volatile("s_waitcnt vmcnt(" VM_ ")" ::: "memory");                   \
    __builtin_amdgcn_s_barrier();                                            \
    __builtin_amdgcn_sched_barrier(0);                                       \
  }
#define NPH(PRB_, AO_, BO_, STG_)                                            \
  {                                                                          \
    STG_                                                                     \
    const char* ab_ = lds + (PRB_) + (AO_) + aro;                            \
    _Pragma("unroll") for (int mi = 0; mi < 4; mi++)                         \
      af[mi] = *(const short8*)(ab_ + mi * 1024);                            \
    const char* bb_ = lds + (PRB_) + (BO_) + bro;                            \
    _Pragma("unroll") for (int ni = 0; ni < 4; ni++)                         \
      bf[ni] = *(const short8*)(bb_ + ni * 1024);                            \
    asm volatile("s_waitcnt lgkmcnt(0)" ::: "memory");                       \
    __builtin_amdgcn_sched_barrier(0);                                       \
    __builtin_amdgcn_s_setprio(1);                                           \
    _Pragma("unroll") for (int mi = 0; mi < 4; mi++)                         \
      _Pragma("unroll") for (int ni = 0; ni < 4; ni++)                       \
        acc[mi][ni] = mfma16(af[mi], bf[ni], acc[mi][ni]);                   \
    __builtin_amdgcn_s_setprio(0);                                           \
  }

  NSTGA(0, 0)      NSTGB(16384, 0)
  NSTGA(24576, 32) NSTGB(40960, 32)
  NSTGA(49152, 64) NSTGB(65536, 64)

  for (int t = 0; t < 62; t += 2) {
    const int ka = (t + 1) * 64 + 32;
    const int kb = (t + 2) * 64;
    NSYNC("3") NPH(0, 0, 16384,     NSTGA(49152 + 24576, ka) NSTGB(49152 + 40960, ka))
    NSYNC("3") NPH(0, 24576, 40960, NSTGA(0, kb) NSTGB(16384, kb))
    const int kc = (t + 2) * 64 + 32;
    const int kd = (t + 3) * 64;
    NSYNC("3") NPH(49152, 0, 16384,     NSTGA(24576, kc) NSTGB(40960, kc))
    NSYNC("3") NPH(49152, 24576, 40960, NSTGA(49152, kd) NSTGB(49152 + 16384, kd))
  }
  NSYNC("3") NPH(0, 0, 16384,     NSTGA(49152 + 24576, 63 * 64 + 32) NSTGB(49152 + 40960, 63 * 64 + 32))
  NSYNC("3") NPH(0, 24576, 40960, )
  NSYNC("3") NPH(49152, 0, 16384, )
  NSYNC("0") NPH(49152, 24576, 40960, )

#undef NPH
#undef NSYNC
#undef NSTGB
#undef NSTGA

#pragma unroll
  for (int mi = 0; mi < 4; mi++) {
#pragma unroll
    for (int ni = 0; ni < 4; ni++) {
      long col = n0 + wn * 64 + ni * 16 + lr;
      f32x4 v = acc[mi][ni];
#pragma unroll
      for (int j = 0; j < 4; j++) {
        long row = m0 + wm * 64 + mi * 16 + lg * 4 + j;
        CF[row * 4096 + col] = v[j];
      }
    }
  }
}

// ---------------------------------------------------------------------------
// Merged K-RoPE + V transpose: grid (2048, 2). (round-12 verified, unchanged)
// ---------------------------------------------------------------------------
__global__ __launch_bounds__(256) void prep_qkv(
    bf16* __restrict__ Kb,
    const float* __restrict__ FC, const float* __restrict__ FS,
    const bf16* __restrict__ V, bf16* __restrict__ VT)
{
  const int t = threadIdx.x;
  if (blockIdx.y == 0) {
    const int row = blockIdx.x;
    const int s = row & 1023;
    bf16* base = Kb + (long)row * 4096 + t * 16;
    short8 v0 = *(const short8*)base;
    short8 v1 = *(const short8*)(base + 8);
    const float* cp = FC + s * 64 + (t & 7) * 8;
    const float* sp = FS + s * 64 + (t & 7) * 8;
    f32x4 c0 = *(const f32x4*)cp;
    f32x4 c1 = *(const f32x4*)(cp + 4);
    f32x4 s0 = *(const f32x4*)sp;
    f32x4 s1 = *(const f32x4*)(sp + 4);
    short8 o0, o1;
#pragma unroll
    for (int j = 0; j < 4; j++) {
      float c = c0[j], sn = s0[j];
      float e = bf2f(v0[2 * j]), od = bf2f(v0[2 * j + 1]);
      o0[2 * j] = f2bf(e * c - od * sn);
      o0[2 * j + 1] = f2bf(e * sn + od * c);
      float c2 = c1[j], sn2 = s1[j];
      float e2 = bf2f(v1[2 * j]), od2 = bf2f(v1[2 * j + 1]);
      o1[2 * j] = f2bf(e2 * c2 - od2 * sn2);
      o1[2 * j + 1] = f2bf(e2 * sn2 + od2 * c2);
    }
    *(short8*)base = o0;
    *(short8*)(base + 8) = o1;
    return;
  }
  if (blockIdx.x >= 1024) return;
  __shared__ bf16 T[64 * 128];
  const int st = (blockIdx.x & 15) * 64, bh = blockIdx.x >> 4;
  const int b = bh >> 5, h = bh & 31;
  const bf16* src = V + ((long)(b * 1024 + st)) * 4096 + h * 128;
#pragma unroll
  for (int rr = 0; rr < 4; ++rr) {
    int i = t + rr * 256;
    int s_l = i >> 4, c = i & 15;
    short8 v = *(const short8*)(src + (long)s_l * 4096 + c * 8);
    *(short8*)((char*)T + s_l * 256 + ((c ^ (s_l & 7)) * 16)) = v;
  }
  __syncthreads();
#pragma unroll
  for (int rr = 0; rr < 4; ++rr) {
    int i = t + rr * 256;
    int d = i >> 3, cs = i & 7;
    short8 ov;
#pragma unroll
    for (int e = 0; e < 8; e++) {
      int s_l = cs * 8 + e;
      ov[e] = *(const short*)((char*)T + s_l * 256 + (((d >> 3) ^ (s_l & 7)) * 16) + (d & 7) * 2);
    }
    *(short8*)(VT + ((long)bh * 128 + d) * 1024 + st + cs * 8) = ov;
  }
}

// ---------------------------------------------------------------------------
// Flash attention v3c: round-12 verified pipeline + T5 setprio around the
// QK^T and PV MFMA clusters (pure scheduler hint, no numeric change).
// ---------------------------------------------------------------------------
__global__ __launch_bounds__(256) void flash_attn(
    const bf16* __restrict__ Q, const bf16* __restrict__ Kg, const bf16* __restrict__ VT,
    const bf16* __restrict__ PK, const bf16* __restrict__ PV,
    const float* __restrict__ GATE, const float* __restrict__ FC,
    const float* __restrict__ FS, bf16* __restrict__ O)
{
  __shared__ bf16 Kl[2][64 * 128];
  __shared__ bf16 Vl[2][128 * 64];
  __shared__ bf16 PKl[16 * 128];
  __shared__ bf16 PVl[128 * 16];
  __shared__ bf16 Pl[4][16 * 64];
  const int tid = threadIdx.x, w = tid >> 6, l = tid & 63;
  const int lg = l >> 4, lr = l & 15;
  const int qb = blockIdx.x, bh = blockIdx.y;
  const int b = bh >> 5, h = bh & 31;
  const int q0 = qb * 64 + w * 16;

  short8 qf[4];
  {
    const bf16* qp = Q + ((long)(b * 1024 + q0 + lr)) * 4096 + h * 128 + lg * 8;
    const int s = q0 + lr;
#pragma unroll
    for (int c = 0; c < 4; c++) {
      short8 v = *(const short8*)(qp + c * 32);
      f32x4 fc = *(const f32x4*)(FC + s * 64 + c * 16 + lg * 4);
      f32x4 fs = *(const f32x4*)(FS + s * 64 + c * 16 + lg * 4);
#pragma unroll
      for (int j = 0; j < 4; j++) {
        float e = bf2f(v[2 * j]), od = bf2f(v[2 * j + 1]);
        v[2 * j] = f2bf(e * fc[j] - od * fs[j]);
        v[2 * j + 1] = f2bf(e * fs[j] + od * fc[j]);
      }
      qf[c] = v;
    }
  }
  {
    int rowp = tid >> 4, pc = tid & 15, lc = pc ^ (rowp & 7);
    short8 v = {0, 0, 0, 0, 0, 0, 0, 0};
    if (rowp < 10) v = *(const short8*)(PK + (long)rowp * 4096 + h * 128 + lc * 8);
    *(short8*)((char*)PKl + tid * 16) = v;
  }
  {
    int d = tid >> 1, pb = (tid & 1) * 8;
#pragma unroll
    for (int e = 0; e < 8; e++) {
      int p = pb + e;
      short v = 0;
      if (p < 10) v = __builtin_bit_cast(short, PV[(long)p * 4096 + h * 128 + d]);
      *(short*)((char*)PVl + d * 32 + (((p >> 3) ^ (d & 1)) * 16) + (p & 7) * 2) = v;
    }
  }
  const float gate = GATE[h];

  f32x4 o[8];
#pragma unroll
  for (int i = 0; i < 8; i++) o[i] = (f32x4){0.f, 0.f, 0.f, 0.f};
  float m_[4] = {-1e30f, -1e30f, -1e30f, -1e30f};
  float l_[4] = {0.f, 0.f, 0.f, 0.f};

  const int nt = qb + 1;   // 64-key tiles
  const bf16* Kbase = Kg + ((long)b * 1024) * 4096 + h * 128;
  const bf16* Vbase = VT + ((long)bh) * 128 * 1024;
  bf16* pw = &Pl[w][0];

#define FSTG(BUF_, J_)                                                        \
  {                                                                           \
    _Pragma("unroll") for (int r_ = 0; r_ < 4; ++r_) {                        \
      int i_ = tid + 256 * r_;                                                \
      int kr_ = i_ >> 4, kc_ = (i_ & 15) ^ (kr_ & 7);                         \
      gl_lds16(Kbase + (long)((J_) * 64 + kr_) * 4096 + kc_ * 8,              \
               &Kl[BUF_][0] + i_ * 8);                                        \
      int vd_ = i_ >> 3, vc_ = (i_ & 7) ^ (vd_ & 7);                          \
      gl_lds16(Vbase + (long)vd_ * 1024 + (J_) * 64 + vc_ * 8,                \
               &Vl[BUF_][0] + i_ * 8);                                        \
    }                                                                         \
  }

  FSTG(0, 0)
  for (int j = 0; j < nt; ++j) {
    __builtin_amdgcn_s_barrier();
    if (j + 1 < nt) {
      FSTG((j + 1) & 1, j + 1)
      asm volatile("s_waitcnt vmcnt(8)" ::: "memory");
    } else {
      asm volatile("s_waitcnt vmcnt(0)" ::: "memory");
    }
    __builtin_amdgcn_s_barrier();
    __builtin_amdgcn_sched_barrier(0);

    const char* kb = (const char*)&Kl[j & 1][0];
    const char* vb = (const char*)&Vl[j & 1][0];

    f32x4 s[4];
    __builtin_amdgcn_s_setprio(1);
#pragma unroll
    for (int ns = 0; ns < 4; ns++) {
      f32x4 a = (f32x4){0.f, 0.f, 0.f, 0.f};
      int krow = ns * 16 + lr;
      int sw = krow & 7;
#pragma unroll
      for (int c = 0; c < 4; c++) {
        short8 kf = *(const short8*)(kb + krow * 256 + (((c * 4 + lg) ^ sw) * 16));
        a = mfma16(qf[c], kf, a);
      }
      int key = j * 64 + krow;
#pragma unroll
      for (int r = 0; r < 4; r++) {
        int qr = q0 + lg * 4 + r;
        s[ns][r] = a[r] * SCALE_ + ((key <= qr) ? 0.0f : -1e30f);
      }
    }
    __builtin_amdgcn_s_setprio(0);
    // online softmax over 64 keys (always-rescale, verified)
    float mx[4], cor[4], sum[4];
#pragma unroll
    for (int r = 0; r < 4; r++)
      mx[r] = fmaxf(fmaxf(s[0][r], s[1][r]), fmaxf(s[2][r], s[3][r]));
#pragma unroll
    for (int xm = 1; xm < 16; xm <<= 1)
#pragma unroll
      for (int r = 0; r < 4; r++) mx[r] = fmaxf(mx[r], __shfl_xor(mx[r], xm, 64));
#pragma unroll
    for (int r = 0; r < 4; r++) {
      float mn = fmaxf(m_[r], mx[r]);
      cor[r] = __expf(m_[r] - mn);
      m_[r] = mn;
      sum[r] = 0.f;
    }
#pragma unroll
    for (int ns = 0; ns < 4; ns++)
#pragma unroll
      for (int r = 0; r < 4; r++) {
        s[ns][r] = __expf(s[ns][r] - m_[r]);
        sum[r] += s[ns][r];
      }
#pragma unroll
    for (int xm = 1; xm < 16; xm <<= 1)
#pragma unroll
      for (int r = 0; r < 4; r++) sum[r] += __shfl_xor(sum[r], xm, 64);
#pragma unroll
    for (int r = 0; r < 4; r++) l_[r] = l_[r] * cor[r] + sum[r];
#pragma unroll
    for (int df = 0; df < 8; df++)
#pragma unroll
      for (int r = 0; r < 4; r++) o[df][r] *= cor[r];

    // P (C-layout) -> per-wave swizzled LDS -> A-frags
#pragma unroll
    for (int ns = 0; ns < 4; ns++)
#pragma unroll
      for (int r = 0; r < 4; r++) {
        int row = lg * 4 + r;
        int ch = ns * 2 + (lr >> 3);
        *(short*)((char*)pw + row * 128 + ((ch ^ (row & 7)) * 16) + (lr & 7) * 2)
            = f2bf(s[ns][r]);
      }
    asm volatile("s_waitcnt lgkmcnt(0)" ::: "memory");
    __builtin_amdgcn_sched_barrier(0);
    short8 pf0 = *(const short8*)((char*)pw + lr * 128 + ((lg ^ (lr & 7)) * 16));
    short8 pf1 = *(const short8*)((char*)pw + lr * 128 + (((4 + lg) ^ (lr & 7)) * 16));

    __builtin_amdgcn_s_setprio(1);
#pragma unroll
    for (int df = 0; df < 8; df++) {
      int d = df * 16 + lr;
      short8 vf0 = *(const short8*)(vb + d * 128 + ((lg ^ (d & 7)) * 16));
      short8 vf1 = *(const short8*)(vb + d * 128 + (((4 + lg) ^ (d & 7)) * 16));
      o[df] = mfma16(pf0, vf0, o[df]);
      o[df] = mfma16(pf1, vf1, o[df]);
    }
    __builtin_amdgcn_s_setprio(0);
  }
#undef FSTG

  // ---- prompt attention (separate softmax, gated) ----
  f32x4 ps;
  {
    f32x4 a = (f32x4){0.f, 0.f, 0.f, 0.f};
    const char* kp = (const char*)PKl + lr * 256;
    int sw = lr & 7;
#pragma unroll
    for (int c = 0; c < 4; c++) {
      short8 kf = *(const short8*)(kp + (((c * 4 + lg) ^ sw) * 16));
      a = mfma16(qf[c], kf, a);
    }
#pragma unroll
    for (int r = 0; r < 4; r++) ps[r] = (lr < 10) ? a[r] * SCALE_ : -1e30f;
  }
  {
    float pm[4], pss[4];
#pragma unroll
    for (int r = 0; r < 4; r++) pm[r] = ps[r];
#pragma unroll
    for (int xm = 1; xm < 16; xm <<= 1)
#pragma unroll
      for (int r = 0; r < 4; r++) pm[r] = fmaxf(pm[r], __shfl_xor(pm[r], xm, 64));
#pragma unroll
    for (int r = 0; r < 4; r++) { ps[r] = __expf(ps[r] - pm[r]); pss[r] = ps[r]; }
#pragma unroll
    for (int xm = 1; xm < 16; xm <<= 1)
#pragma unroll
      for (int r = 0; r < 4; r++) pss[r] += __shfl_xor(pss[r], xm, 64);
#pragma unroll
    for (int r = 0; r < 4; r++) ps[r] = ps[r] / pss[r];
  }
#pragma unroll
  for (int r = 0; r < 4; r++) {
    int row = lg * 4 + r;
    int ch0 = (lr >> 3);
    *(short*)((char*)pw + row * 128 + ((ch0 ^ (row & 7)) * 16) + (lr & 7) * 2) = f2bf(ps[r]);
    int ch1 = 2 + (lr >> 3);
    *(short*)((char*)pw + row * 128 + ((ch1 ^ (row & 7)) * 16) + (lr & 7) * 2) = 0;
  }
  asm volatile("s_waitcnt lgkmcnt(0)" ::: "memory");
  __builtin_amdgcn_sched_barrier(0);
  short8 pf2 = *(const short8*)((char*)pw + lr * 128 + ((lg ^ (lr & 7)) * 16));
  f32x4 po[8];
#pragma unroll
  for (int df = 0; df < 8; df++) {
    int d = df * 16 + lr;
    short8 vf = {0, 0, 0, 0, 0, 0, 0, 0};
    if (lg < 2) vf = *(const short8*)((const char*)PVl + d * 32 + ((lg ^ (d & 1)) * 16));
    po[df] = mfma16(pf2, vf, (f32x4){0.f, 0.f, 0.f, 0.f});
  }

  bf16* op = O + ((long)(b * 1024 + q0 + lg * 4)) * 4096 + h * 128 + lr;
#pragma unroll
  for (int df = 0; df < 8; df++)
#pragma unroll
    for (int r = 0; r < 4; r++) {
      float val = o[df][r] / l_[r] + gate * po[df][r];
      *(short*)(op + (long)r * 4096 + df * 16) = f2bf(val);
    }
}

// ---------------------------------------------------------------------------
extern "C" void kernel_launch(void* const* d_in, const int* in_sizes, int n_in,
                              void* d_out, int out_size, void* d_ws, size_t ws_size,
                              hipStream_t stream) {
  (void)in_sizes; (void)n_in; (void)out_size; (void)ws_size;
  const float* x      = (const float*)d_in[0];
  const float* wq     = (const float*)d_in[1];
  const float* wk     = (const float*)d_in[2];
  const float* wv     = (const float*)d_in[3];
  const float* wo     = (const float*)d_in[4];
  const float* prompt = (const float*)d_in[5];
  const float* gate   = (const float*)d_in[6];
  const float* fcos   = (const float*)d_in[7];
  const float* fsin   = (const float*)d_in[8];
  float* out = (float*)d_out;
  char* ws = (char*)d_ws;

  size_t o = 0;
  bf16* xb  = (bf16*)(ws + o); o += (size_t)8388608 * 2;
  bf16* wqb = (bf16*)(ws + o); o += (size_t)16777216 * 2;
  bf16* wkb = (bf16*)(ws + o); o += (size_t)16777216 * 2;
  bf16* wvb = (bf16*)(ws + o); o += (size_t)16777216 * 2;
  bf16* wob = (bf16*)(ws + o); o += (size_t)16777216 * 2;
  bf16* pb  = (bf16*)(ws + o); o += (size_t)40960 * 2;
  bf16* q_ws  = (bf16*)(ws + o); o += (size_t)2048 * 4096 * 2;
  bf16* k_ws  = (bf16*)(ws + o); o += (size_t)2048 * 4096 * 2;
  bf16* v_ws  = (bf16*)(ws + o); o += (size_t)2048 * 4096 * 2;
  bf16* vT_ws = (bf16*)(ws + o); o += (size_t)2048 * 4096 * 2;
  bf16* pk_ws = (bf16*)(ws + o); o += (size_t)40960 * 2;
  bf16* pv_ws = (bf16*)(ws + o); o += (size_t)40960 * 2;
  bf16* attn_ws = v_ws;

  // 1. downcast inputs to bf16
  cvt6<<<dim3(36884), 256, 0, stream>>>(x, wq, wk, wv, wo, prompt,
                                        xb, wqb, wkb, wvb, wob, pb);
  // 2. QKV (+prompt K/V rows): 9 m-tiles x 16 n-tiles per z
  gemm_bt<<<dim3(144, 1, 3), 512, 0, stream>>>(
      xb, pb, wqb, wkb, wvb, q_ws, k_ws, v_ws, pk_ws, pv_ws, 2048, 2058);
  // 3. K-RoPE + V->VT (Q-RoPE fused into flash)
  prep_qkv<<<dim3(2048, 2), 256, 0, stream>>>(k_ws, fcos, fsin, v_ws, vT_ws);
  // 4. flash attention v3c (Q-rope fused, setprio on MFMA clusters)
  flash_attn<<<dim3(16, 64), 256, 0, stream>>>(
      q_ws, k_ws, vT_ws, pk_ws, pv_ws, gate, fcos, fsin, attn_ws);
  // 5. output projection: 256x128 tiles, 256 blocks, f32 out
  gemm_n128<<<dim3(256), 512, 0, stream>>>(attn_ws, wob, out);
}

// Round 14
// 477.640 us; speedup vs baseline: 1.0100x; 1.0100x over previous
//
#include <hip/hip_runtime.h>
#include <hip/hip_bf16.h>
#include <stdint.h>

typedef __hip_bfloat16 bf16;
typedef __attribute__((ext_vector_type(8))) short short8;
typedef __attribute__((ext_vector_type(4))) float f32x4;

#define SCALE_ 0.08838834764831845f  // 1/sqrt(128)

static __device__ __forceinline__ float bf2f(short u) {
  unsigned int x = ((unsigned int)(unsigned short)u) << 16;
  return __builtin_bit_cast(float, x);
}
static __device__ __forceinline__ short f2bf(float f) {
  __hip_bfloat16 h = __float2bfloat16(f);
  return __builtin_bit_cast(short, h);
}
static __device__ __forceinline__ f32x4 mfma16(short8 a, short8 b, f32x4 c) {
  return __builtin_amdgcn_mfma_f32_16x16x32_bf16(a, b, c, 0, 0, 0);
}
static __device__ __forceinline__ void gl_lds16(const bf16* g, bf16* l) {
  __builtin_amdgcn_global_load_lds(
      (const __attribute__((address_space(1))) unsigned int*)g,
      (__attribute__((address_space(3))) unsigned int*)l, 16, 0, 0);
}

// ---------------------------------------------------------------------------
// f32 -> bf16 conversion for x, wq, wk, wv, wo, prompt (one fused launch).
// ---------------------------------------------------------------------------
__global__ __launch_bounds__(256) void cvt6(
    const float* __restrict__ sx, const float* __restrict__ sq,
    const float* __restrict__ sk, const float* __restrict__ sv,
    const float* __restrict__ so, const float* __restrict__ sp,
    bf16* __restrict__ dx, bf16* __restrict__ dq, bf16* __restrict__ dk,
    bf16* __restrict__ dv, bf16* __restrict__ d4, bf16* __restrict__ dp)
{
  int b = blockIdx.x;
  const float* s; bf16* d; int off;
  if (b < 4096)       { s = sx; d = dx; off = b; }
  else if (b < 12288) { s = sq; d = dq; off = b - 4096; }
  else if (b < 20480) { s = sk; d = dk; off = b - 12288; }
  else if (b < 28672) { s = sv; d = dv; off = b - 20480; }
  else if (b < 36864) { s = so; d = d4; off = b - 28672; }
  else                { s = sp; d = dp; off = b - 36864; }
  long base = (long)off * 2048 + threadIdx.x * 8;
  f32x4 a = *(const f32x4*)(s + base);
  f32x4 c = *(const f32x4*)(s + base + 4);
  short8 o;
#pragma unroll
  for (int j = 0; j < 4; j++) { o[j] = f2bf(a[j]); o[4 + j] = f2bf(c[j]); }
  *(short8*)(d + base) = o;
}

// ---------------------------------------------------------------------------
// QKV GEMM v2 — hoisted-read 8-phase schedule (round-13 verified, frozen).
// ---------------------------------------------------------------------------
__global__ __launch_bounds__(512, 2) void gemm_bt(
    const bf16* __restrict__ A, const bf16* __restrict__ A2,
    const bf16* __restrict__ B0, const bf16* __restrict__ B1, const bf16* __restrict__ B2w,
    bf16* __restrict__ C0, bf16* __restrict__ C1, bf16* __restrict__ C2,
    bf16* __restrict__ P1, bf16* __restrict__ P2,
    int M1, int Mtot)
{
  __shared__ char lds[131072];   // 8 slots x 16KB
  const int tid = threadIdx.x, w = tid >> 6, l = tid & 63;
  const int lr = l & 15, lg = l >> 4;
  const int wm = w >> 2, wn = w & 3;
  const int z = blockIdx.z;
  const bf16* Bw = (z == 0) ? B0 : ((z == 1) ? B1 : B2w);
  bf16* C  = (z == 0) ? C0 : ((z == 1) ? C1 : C2);
  bf16* Cp = (z == 0) ? (bf16*)0 : ((z == 1) ? P1 : P2);

  const int cpx = gridDim.x >> 3, orig = blockIdx.x;
  const int wg = (orig & 7) * cpx + (orig >> 3);
  const long m0 = (long)(wg >> 4) * 256;
  const long n0 = (long)(wg & 15) * 256;

  const int r0 = ((tid >> 3) << 1) | ((tid >> 2) & 1);
  const int c0 = (tid & 3) ^ ((tid >> 3) & 3);
  const bf16 *pa0, *pa1;
  {
    long mx = (long)(Mtot - M1) - 1;
    long g0 = m0 + r0, g1 = m0 + r0 + 128;
    const bf16 *q0, *q1;
    if (g0 < M1) q0 = A + g0 * 4096;
    else { long rr = g0 - M1; if (rr > mx) rr = mx; q0 = A2 + rr * 4096; }
    if (g1 < M1) q1 = A + g1 * 4096;
    else { long rr = g1 - M1; if (rr > mx) rr = mx; q1 = A2 + rr * 4096; }
    pa0 = q0 + c0 * 8;
    pa1 = q1 + c0 * 8;
  }
  const bf16* pb0 = Bw + (n0 + r0) * 4096 + c0 * 8;
  const bf16* pb1 = pb0 + (long)128 * 4096;

  const int ro  = (lr >> 1) * 128 + (((lr & 1) * 4) + (lg ^ ((lr >> 1) & 3))) * 16;
  const int aro = wm * 8192 + ro;
  const int bro = wn * 4096 + ro;

  f32x4 acc[8][4];
#pragma unroll
  for (int i = 0; i < 8; i++)
#pragma unroll
    for (int j = 0; j < 4; j++) acc[i][j] = (f32x4){0.f, 0.f, 0.f, 0.f};

  short8 afA[4], afB[4], bfA[4], bfB[4];

#define SGA(BASE_, KE_)                                                      \
  {                                                                          \
    bf16* d_ = (bf16*)(lds + (BASE_)) + tid * 8;                             \
    gl_lds16(pa0 + (KE_), d_);                                               \
    gl_lds16(pa1 + (KE_), d_ + 4096);                                        \
  }
#define SGB(BASE_, KE_)                                                      \
  {                                                                          \
    bf16* d_ = (bf16*)(lds + (BASE_)) + tid * 8;                             \
    gl_lds16(pb0 + (KE_), d_);                                               \
    gl_lds16(pb1 + (KE_), d_ + 4096);                                        \
  }
#define RDA(SET_, BASE_, MO_)                                                \
  _Pragma("unroll") for (int mi = 0; mi < 4; mi++)                           \
    SET_[mi] = *(const short8*)(lds + (BASE_) + aro + ((MO_) + mi) * 1024);
#define RDB(SET_, BASE_)                                                     \
  _Pragma("unroll") for (int ni = 0; ni < 4; ni++)                           \
    SET_[ni] = *(const short8*)(lds + (BASE_) + bro + ni * 1024);
#define VMC(N_) asm volatile("s_waitcnt vmcnt(" N_ ")" ::: "memory");
#define WAITK(N_)                                                            \
  asm volatile("s_waitcnt lgkmcnt(" N_ ")" ::: "memory");                    \
  __builtin_amdgcn_sched_barrier(0);                                         \
  __builtin_amdgcn_s_barrier();                                              \
  __builtin_amdgcn_sched_barrier(0);
#define MM(AF_, BF_, MO_)                                                    \
  __builtin_amdgcn_s_setprio(1);                                             \
  _Pragma("unroll") for (int mi = 0; mi < 4; mi++)                           \
    _Pragma("unroll") for (int ni = 0; ni < 4; ni++)                         \
      acc[(MO_) + mi][ni] = mfma16(AF_[mi], BF_[ni], acc[(MO_) + mi][ni]);   \
  __builtin_amdgcn_s_setprio(0);

  SGA(0, 0) SGB(16384, 0) SGA(32768, 32) SGB(49152, 32)
  SGA(65536, 64) SGB(65536 + 16384, 64)
  VMC("8")
  __builtin_amdgcn_s_barrier();
  __builtin_amdgcn_sched_barrier(0);
  RDA(afA, 0, 0) RDB(bfA, 16384)

  for (int t = 0; t < 62; t += 2) {
    const int ka = (t + 1) * 64 + 32, kb = (t + 2) * 64;
    const int kc = (t + 2) * 64 + 32, kd = (t + 3) * 64;
    SGA(65536 + 32768, ka) RDA(afB, 0, 4)                              WAITK("4") MM(afA, bfA, 0)
    SGB(65536 + 49152, ka) VMC("8") RDA(afA, 32768, 0) RDB(bfB, 49152) WAITK("8") MM(afB, bfA, 4)
    SGA(0, kb)             RDA(afB, 32768, 4)                          WAITK("4") MM(afA, bfB, 0)
    SGB(16384, kb)         VMC("8") RDA(afA, 65536, 0) RDB(bfA, 65536 + 16384) WAITK("8") MM(afB, bfB, 4)
    SGA(32768, kc)         RDA(afB, 65536, 4)                          WAITK("4") MM(afA, bfA, 0)
    SGB(49152, kc)         VMC("8") RDA(afA, 65536 + 32768, 0) RDB(bfB, 65536 + 49152) WAITK("8") MM(afB, bfA, 4)
    SGA(65536, kd)         RDA(afB, 65536 + 32768, 4)                  WAITK("4") MM(afA, bfB, 0)
    SGB(65536 + 16384, kd) VMC("8") RDA(afA, 0, 0) RDB(bfA, 16384)     WAITK("8") MM(afB, bfB, 4)
  }
  SGA(65536 + 32768, 4064) RDA(afB, 0, 4)                              WAITK("4") MM(afA, bfA, 0)
  SGB(65536 + 49152, 4064) VMC("8") RDA(afA, 32768, 0) RDB(bfB, 49152) WAITK("8") MM(afB, bfA, 4)
  RDA(afB, 32768, 4)                                                   WAITK("4") MM(afA, bfB, 0)
  VMC("4") RDA(afA, 65536, 0) RDB(bfA, 65536 + 16384)                  WAITK("8") MM(afB, bfB, 4)
  RDA(afB, 65536, 4)                                                   WAITK("4") MM(afA, bfA, 0)
  VMC("0") RDA(afA, 65536 + 32768, 0) RDB(bfB, 65536 + 49152)          WAITK("8") MM(afB, bfA, 4)
  RDA(afB, 65536 + 32768, 4)                                           WAITK("4") MM(afA, bfB, 0)
  WAITK("0") MM(afB, bfB, 4)

#undef MM
#undef WAITK
#undef VMC
#undef RDB
#undef RDA
#undef SGB
#undef SGA

#pragma unroll
  for (int mi = 0; mi < 8; mi++) {
#pragma unroll
    for (int ni = 0; ni < 4; ni++) {
      long col = n0 + wn * 64 + ni * 16 + lr;
      f32x4 v = acc[mi][ni];
#pragma unroll
      for (int j = 0; j < 4; j++) {
        long row = m0 + wm * 128 + mi * 16 + lg * 4 + j;
        if (row < M1) {
          *(short*)(C + row * 4096 + col) = f2bf(v[j]);
        } else if (Cp != 0 && row < Mtot) {
          *(short*)(Cp + (row - M1) * 4096 + col) = f2bf(v[j]);
        }
      }
    }
  }
}

// ---------------------------------------------------------------------------
// Out-projection GEMM (round-9/10/12 verified, unchanged): 256x128, 256 blocks.
// ---------------------------------------------------------------------------
__global__ __launch_bounds__(512, 2) void gemm_n128(
    const bf16* __restrict__ A, const bf16* __restrict__ Bw,
    float* __restrict__ CF)
{
  __shared__ char lds[98304];
  const int tid = threadIdx.x, w = tid >> 6, l = tid & 63;
  const int lr = l & 15, lg = l >> 4;
  const int wm = w >> 1, wn = w & 1;

  const int cpx = gridDim.x >> 3, orig = blockIdx.x;
  const int wg = (orig & 7) * cpx + (orig >> 3);
  const long m0 = (long)(wg >> 5) * 256;
  const long n0 = (long)(wg & 31) * 128;

  const int r0 = ((tid >> 3) << 1) | ((tid >> 2) & 1);
  const int c0 = (tid & 3) ^ ((tid >> 3) & 3);
  const bf16* pa0 = A + (m0 + r0) * 4096 + c0 * 8;
  const bf16* pa1 = pa0 + (long)128 * 4096;
  const bf16* pb0 = Bw + (n0 + r0) * 4096 + c0 * 8;

  const int ro  = (lr >> 1) * 128 + (((lr & 1) * 4) + (lg ^ ((lr >> 1) & 3))) * 16;
  const int aro = wm * 4096 + ro;
  const int bro = wn * 4096 + ro;

  f32x4 acc[4][4];
#pragma unroll
  for (int i = 0; i < 4; i++)
#pragma unroll
    for (int j = 0; j < 4; j++) acc[i][j] = (f32x4){0.f, 0.f, 0.f, 0.f};

  short8 af[4], bf[4];

#define NSTGA(SB_, KE_)                                                      \
  {                                                                          \
    bf16* d_ = (bf16*)(lds + (SB_)) + tid * 8;                               \
    gl_lds16(pa0 + (KE_), d_);                                               \
    gl_lds16(pa1 + (KE_), d_ + 4096);                                        \
  }
#define NSTGB(SB_, KE_)                                                      \
  {                                                                          \
    bf16* d_ = (bf16*)(lds + (SB_)) + tid * 8;                               \
    gl_lds16(pb0 + (KE_), d_);                                               \
  }
#define NSYNC(VM_)                                                           \
  {                                                                          \
    asm volatile("s_waitcnt vmcnt(" VM_ ")" ::: "memory");                   \
    __builtin_amdgcn_s_barrier();                                            \
    __builtin_amdgcn_sched_barrier(0);                                       \
  }
#define NPH(PRB_, AO_, BO_, STG_)                                            \
  {                                                                          \
    STG_                                                                     \
    const char* ab_ = lds + (PRB_) + (AO_) + aro;                            \
    _Pragma("unroll") for (int mi = 0; mi < 4; mi++)                         \
      af[mi] = *(const short8*)(ab_ + mi * 1024);                            \
    const char* bb_ = lds + (PRB_) + (BO_) + bro;                            \
    _Pragma("unroll") for (int ni = 0; ni < 4; ni++)                         \
      bf[ni] = *(const short8*)(bb_ + ni * 1024);                            \
    asm volatile("s_waitcnt lgkmcnt(0)" ::: "memory");                       \
    __builtin_amdgcn_sched_barrier(0);                                       \
    __builtin_amdgcn_s_setprio(1);                                           \
    _Pragma("unroll") for (int mi = 0; mi < 4; mi++)                         \
      _Pragma("unroll") for (int ni = 0; ni < 4; ni++)                       \
        acc[mi][ni] = mfma16(af[mi], bf[ni], acc[mi][ni]);                   \
    __builtin_amdgcn_s_setprio(0);                                           \
  }

  NSTGA(0, 0)      NSTGB(16384, 0)
  NSTGA(24576, 32) NSTGB(40960, 32)
  NSTGA(49152, 64) NSTGB(65536, 64)

  for (int t = 0; t < 62; t += 2) {
    const int ka = (t + 1) * 64 + 32;
    const int kb = (t + 2) * 64;
    NSYNC("3") NPH(0, 0, 16384,     NSTGA(49152 + 24576, ka) NSTGB(49152 + 40960, ka))
    NSYNC("3") NPH(0, 24576, 40960, NSTGA(0, kb) NSTGB(16384, kb))
    const int kc = (t + 2) * 64 + 32;
    const int kd = (t + 3) * 64;
    NSYNC("3") NPH(49152, 0, 16384,     NSTGA(24576, kc) NSTGB(40960, kc))
    NSYNC("3") NPH(49152, 24576, 40960, NSTGA(49152, kd) NSTGB(49152 + 16384, kd))
  }
  NSYNC("3") NPH(0, 0, 16384,     NSTGA(49152 + 24576, 63 * 64 + 32) NSTGB(49152 + 40960, 63 * 64 + 32))
  NSYNC("3") NPH(0, 24576, 40960, )
  NSYNC("3") NPH(49152, 0, 16384, )
  NSYNC("0") NPH(49152, 24576, 40960, )

#undef NPH
#undef NSYNC
#undef NSTGB
#undef NSTGA

#pragma unroll
  for (int mi = 0; mi < 4; mi++) {
#pragma unroll
    for (int ni = 0; ni < 4; ni++) {
      long col = n0 + wn * 64 + ni * 16 + lr;
      f32x4 v = acc[mi][ni];
#pragma unroll
      for (int j = 0; j < 4; j++) {
        long row = m0 + wm * 64 + mi * 16 + lg * 4 + j;
        CF[row * 4096 + col] = v[j];
      }
    }
  }
}

// ---------------------------------------------------------------------------
// Merged K-RoPE + V transpose: grid (2048, 2). (round-12 verified, unchanged)
// ---------------------------------------------------------------------------
__global__ __launch_bounds__(256) void prep_qkv(
    bf16* __restrict__ Kb,
    const float* __restrict__ FC, const float* __restrict__ FS,
    const bf16* __restrict__ V, bf16* __restrict__ VT)
{
  const int t = threadIdx.x;
  if (blockIdx.y == 0) {
    const int row = blockIdx.x;
    const int s = row & 1023;
    bf16* base = Kb + (long)row * 4096 + t * 16;
    short8 v0 = *(const short8*)base;
    short8 v1 = *(const short8*)(base + 8);
    const float* cp = FC + s * 64 + (t & 7) * 8;
    const float* sp = FS + s * 64 + (t & 7) * 8;
    f32x4 c0 = *(const f32x4*)cp;
    f32x4 c1 = *(const f32x4*)(cp + 4);
    f32x4 s0 = *(const f32x4*)sp;
    f32x4 s1 = *(const f32x4*)(sp + 4);
    short8 o0, o1;
#pragma unroll
    for (int j = 0; j < 4; j++) {
      float c = c0[j], sn = s0[j];
      float e = bf2f(v0[2 * j]), od = bf2f(v0[2 * j + 1]);
      o0[2 * j] = f2bf(e * c - od * sn);
      o0[2 * j + 1] = f2bf(e * sn + od * c);
      float c2 = c1[j], sn2 = s1[j];
      float e2 = bf2f(v1[2 * j]), od2 = bf2f(v1[2 * j + 1]);
      o1[2 * j] = f2bf(e2 * c2 - od2 * sn2);
      o1[2 * j + 1] = f2bf(e2 * sn2 + od2 * c2);
    }
    *(short8*)base = o0;
    *(short8*)(base + 8) = o1;
    return;
  }
  if (blockIdx.x >= 1024) return;
  __shared__ bf16 T[64 * 128];
  const int st = (blockIdx.x & 15) * 64, bh = blockIdx.x >> 4;
  const int b = bh >> 5, h = bh & 31;
  const bf16* src = V + ((long)(b * 1024 + st)) * 4096 + h * 128;
#pragma unroll
  for (int rr = 0; rr < 4; ++rr) {
    int i = t + rr * 256;
    int s_l = i >> 4, c = i & 15;
    short8 v = *(const short8*)(src + (long)s_l * 4096 + c * 8);
    *(short8*)((char*)T + s_l * 256 + ((c ^ (s_l & 7)) * 16)) = v;
  }
  __syncthreads();
#pragma unroll
  for (int rr = 0; rr < 4; ++rr) {
    int i = t + rr * 256;
    int d = i >> 3, cs = i & 7;
    short8 ov;
#pragma unroll
    for (int e = 0; e < 8; e++) {
      int s_l = cs * 8 + e;
      ov[e] = *(const short*)((char*)T + s_l * 256 + (((d >> 3) ^ (s_l & 7)) * 16) + (d & 7) * 2);
    }
    *(short8*)(VT + ((long)bh * 128 + d) * 1024 + st + cs * 8) = ov;
  }
}

// ---------------------------------------------------------------------------
// Flash attention v3d: round-13 verified kernel + COMPLEMENTARY-PAIR qb
// remap. Work per block is triangular (qb+1 tiles); consecutive blockIdx
// pairs now get (15,0),(14,1),... = constant 17 tiles per pair, fixing the
// per-CU makespan imbalance under contiguous dispatch. Zero numeric change.
// ---------------------------------------------------------------------------
__global__ __launch_bounds__(256) void flash_attn(
    const bf16* __restrict__ Q, const bf16* __restrict__ Kg, const bf16* __restrict__ VT,
    const bf16* __restrict__ PK, const bf16* __restrict__ PV,
    const float* __restrict__ GATE, const float* __restrict__ FC,
    const float* __restrict__ FS, bf16* __restrict__ O)
{
  __shared__ bf16 Kl[2][64 * 128];
  __shared__ bf16 Vl[2][128 * 64];
  __shared__ bf16 PKl[16 * 128];
  __shared__ bf16 PVl[128 * 16];
  __shared__ bf16 Pl[4][16 * 64];
  const int tid = threadIdx.x, w = tid >> 6, l = tid & 63;
  const int lg = l >> 4, lr = l & 15;
  const int qbx = blockIdx.x;
  const int qb = (qbx & 1) ? (qbx >> 1) : (15 - (qbx >> 1));  // pair-balance
  const int bh = blockIdx.y;
  const int b = bh >> 5, h = bh & 31;
  const int q0 = qb * 64 + w * 16;

  short8 qf[4];
  {
    const bf16* qp = Q + ((long)(b * 1024 + q0 + lr)) * 4096 + h * 128 + lg * 8;
    const int s = q0 + lr;
#pragma unroll
    for (int c = 0; c < 4; c++) {
      short8 v = *(const short8*)(qp + c * 32);
      f32x4 fc = *(const f32x4*)(FC + s * 64 + c * 16 + lg * 4);
      f32x4 fs = *(const f32x4*)(FS + s * 64 + c * 16 + lg * 4);
#pragma unroll
      for (int j = 0; j < 4; j++) {
        float e = bf2f(v[2 * j]), od = bf2f(v[2 * j + 1]);
        v[2 * j] = f2bf(e * fc[j] - od * fs[j]);
        v[2 * j + 1] = f2bf(e * fs[j] + od * fc[j]);
      }
      qf[c] = v;
    }
  }
  {
    int rowp = tid >> 4, pc = tid & 15, lc = pc ^ (rowp & 7);
    short8 v = {0, 0, 0, 0, 0, 0, 0, 0};
    if (rowp < 10) v = *(const short8*)(PK + (long)rowp * 4096 + h * 128 + lc * 8);
    *(short8*)((char*)PKl + tid * 16) = v;
  }
  {
    int d = tid >> 1, pb = (tid & 1) * 8;
#pragma unroll
    for (int e = 0; e < 8; e++) {
      int p = pb + e;
      short v = 0;
      if (p < 10) v = __builtin_bit_cast(short, PV[(long)p * 4096 + h * 128 + d]);
      *(short*)((char*)PVl + d * 32 + (((p >> 3) ^ (d & 1)) * 16) + (p & 7) * 2) = v;
    }
  }
  const float gate = GATE[h];

  f32x4 o[8];
#pragma unroll
  for (int i = 0; i < 8; i++) o[i] = (f32x4){0.f, 0.f, 0.f, 0.f};
  float m_[4] = {-1e30f, -1e30f, -1e30f, -1e30f};
  float l_[4] = {0.f, 0.f, 0.f, 0.f};

  const int nt = qb + 1;   // 64-key tiles
  const bf16* Kbase = Kg + ((long)b * 1024) * 4096 + h * 128;
  const bf16* Vbase = VT + ((long)bh) * 128 * 1024;
  bf16* pw = &Pl[w][0];

#define FSTG(BUF_, J_)                                                        \
  {                                                                           \
    _Pragma("unroll") for (int r_ = 0; r_ < 4; ++r_) {                        \
      int i_ = tid + 256 * r_;                                                \
      int kr_ = i_ >> 4, kc_ = (i_ & 15) ^ (kr_ & 7);                         \
      gl_lds16(Kbase + (long)((J_) * 64 + kr_) * 4096 + kc_ * 8,              \
               &Kl[BUF_][0] + i_ * 8);                                        \
      int vd_ = i_ >> 3, vc_ = (i_ & 7) ^ (vd_ & 7);                          \
      gl_lds16(Vbase + (long)vd_ * 1024 + (J_) * 64 + vc_ * 8,                \
               &Vl[BUF_][0] + i_ * 8);                                        \
    }                                                                         \
  }

  FSTG(0, 0)
  for (int j = 0; j < nt; ++j) {
    __builtin_amdgcn_s_barrier();
    if (j + 1 < nt) {
      FSTG((j + 1) & 1, j + 1)
      asm volatile("s_waitcnt vmcnt(8)" ::: "memory");
    } else {
      asm volatile("s_waitcnt vmcnt(0)" ::: "memory");
    }
    __builtin_amdgcn_s_barrier();
    __builtin_amdgcn_sched_barrier(0);

    const char* kb = (const char*)&Kl[j & 1][0];
    const char* vb = (const char*)&Vl[j & 1][0];

    f32x4 s[4];
    __builtin_amdgcn_s_setprio(1);
#pragma unroll
    for (int ns = 0; ns < 4; ns++) {
      f32x4 a = (f32x4){0.f, 0.f, 0.f, 0.f};
      int krow = ns * 16 + lr;
      int sw = krow & 7;
#pragma unroll
      for (int c = 0; c < 4; c++) {
        short8 kf = *(const short8*)(kb + krow * 256 + (((c * 4 + lg) ^ sw) * 16));
        a = mfma16(qf[c], kf, a);
      }
      int key = j * 64 + krow;
#pragma unroll
      for (int r = 0; r < 4; r++) {
        int qr = q0 + lg * 4 + r;
        s[ns][r] = a[r] * SCALE_ + ((key <= qr) ? 0.0f : -1e30f);
      }
    }
    __builtin_amdgcn_s_setprio(0);
    // online softmax over 64 keys (always-rescale, verified)
    float mx[4], cor[4], sum[4];
#pragma unroll
    for (int r = 0; r < 4; r++)
      mx[r] = fmaxf(fmaxf(s[0][r], s[1][r]), fmaxf(s[2][r], s[3][r]));
#pragma unroll
    for (int xm = 1; xm < 16; xm <<= 1)
#pragma unroll
      for (int r = 0; r < 4; r++) mx[r] = fmaxf(mx[r], __shfl_xor(mx[r], xm, 64));
#pragma unroll
    for (int r = 0; r < 4; r++) {
      float mn = fmaxf(m_[r], mx[r]);
      cor[r] = __expf(m_[r] - mn);
      m_[r] = mn;
      sum[r] = 0.f;
    }
#pragma unroll
    for (int ns = 0; ns < 4; ns++)
#pragma unroll
      for (int r = 0; r < 4; r++) {
        s[ns][r] = __expf(s[ns][r] - m_[r]);
        sum[r] += s[ns][r];
      }
#pragma unroll
    for (int xm = 1; xm < 16; xm <<= 1)
#pragma unroll
      for (int r = 0; r < 4; r++) sum[r] += __shfl_xor(sum[r], xm, 64);
#pragma unroll
    for (int r = 0; r < 4; r++) l_[r] = l_[r] * cor[r] + sum[r];
#pragma unroll
    for (int df = 0; df < 8; df++)
#pragma unroll
      for (int r = 0; r < 4; r++) o[df][r] *= cor[r];

    // P (C-layout) -> per-wave swizzled LDS -> A-frags
#pragma unroll
    for (int ns = 0; ns < 4; ns++)
#pragma unroll
      for (int r = 0; r < 4; r++) {
        int row = lg * 4 + r;
        int ch = ns * 2 + (lr >> 3);
        *(short*)((char*)pw + row * 128 + ((ch ^ (row & 7)) * 16) + (lr & 7) * 2)
            = f2bf(s[ns][r]);
      }
    asm volatile("s_waitcnt lgkmcnt(0)" ::: "memory");
    __builtin_amdgcn_sched_barrier(0);
    short8 pf0 = *(const short8*)((char*)pw + lr * 128 + ((lg ^ (lr & 7)) * 16));
    short8 pf1 = *(const short8*)((char*)pw + lr * 128 + (((4 + lg) ^ (lr & 7)) * 16));

    __builtin_amdgcn_s_setprio(1);
#pragma unroll
    for (int df = 0; df < 8; df++) {
      int d = df * 16 + lr;
      short8 vf0 = *(const short8*)(vb + d * 128 + ((lg ^ (d & 7)) * 16));
      short8 vf1 = *(const short8*)(vb + d * 128 + (((4 + lg) ^ (d & 7)) * 16));
      o[df] = mfma16(pf0, vf0, o[df]);
      o[df] = mfma16(pf1, vf1, o[df]);
    }
    __builtin_amdgcn_s_setprio(0);
  }
#undef FSTG

  // ---- prompt attention (separate softmax, gated) ----
  f32x4 ps;
  {
    f32x4 a = (f32x4){0.f, 0.f, 0.f, 0.f};
    const char* kp = (const char*)PKl + lr * 256;
    int sw = lr & 7;
#pragma unroll
    for (int c = 0; c < 4; c++) {
      short8 kf = *(const short8*)(kp + (((c * 4 + lg) ^ sw) * 16));
      a = mfma16(qf[c], kf, a);
    }
#pragma unroll
    for (int r = 0; r < 4; r++) ps[r] = (lr < 10) ? a[r] * SCALE_ : -1e30f;
  }
  {
    float pm[4], pss[4];
#pragma unroll
    for (int r = 0; r < 4; r++) pm[r] = ps[r];
#pragma unroll
    for (int xm = 1; xm < 16; xm <<= 1)
#pragma unroll
      for (int r = 0; r < 4; r++) pm[r] = fmaxf(pm[r], __shfl_xor(pm[r], xm, 64));
#pragma unroll
    for (int r = 0; r < 4; r++) { ps[r] = __expf(ps[r] - pm[r]); pss[r] = ps[r]; }
#pragma unroll
    for (int xm = 1; xm < 16; xm <<= 1)
#pragma unroll
      for (int r = 0; r < 4; r++) pss[r] += __shfl_xor(pss[r], xm, 64);
#pragma unroll
    for (int r = 0; r < 4; r++) ps[r] = ps[r] / pss[r];
  }
#pragma unroll
  for (int r = 0; r < 4; r++) {
    int row = lg * 4 + r;
    int ch0 = (lr >> 3);
    *(short*)((char*)pw + row * 128 + ((ch0 ^ (row & 7)) * 16) + (lr & 7) * 2) = f2bf(ps[r]);
    int ch1 = 2 + (lr >> 3);
    *(short*)((char*)pw + row * 128 + ((ch1 ^ (row & 7)) * 16) + (lr & 7) * 2) = 0;
  }
  asm volatile("s_waitcnt lgkmcnt(0)" ::: "memory");
  __builtin_amdgcn_sched_barrier(0);
  short8 pf2 = *(const short8*)((char*)pw + lr * 128 + ((lg ^ (lr & 7)) * 16));
  f32x4 po[8];
#pragma unroll
  for (int df = 0; df < 8; df++) {
    int d = df * 16 + lr;
    short8 vf = {0, 0, 0, 0, 0, 0, 0, 0};
    if (lg < 2) vf = *(const short8*)((const char*)PVl + d * 32 + ((lg ^ (d & 1)) * 16));
    po[df] = mfma16(pf2, vf, (f32x4){0.f, 0.f, 0.f, 0.f});
  }

  bf16* op = O + ((long)(b * 1024 + q0 + lg * 4)) * 4096 + h * 128 + lr;
#pragma unroll
  for (int df = 0; df < 8; df++)
#pragma unroll
    for (int r = 0; r < 4; r++) {
      float val = o[df][r] / l_[r] + gate * po[df][r];
      *(short*)(op + (long)r * 4096 + df * 16) = f2bf(val);
    }
}

// ---------------------------------------------------------------------------
extern "C" void kernel_launch(void* const* d_in, const int* in_sizes, int n_in,
                              void* d_out, int out_size, void* d_ws, size_t ws_size,
                              hipStream_t stream) {
  (void)in_sizes; (void)n_in; (void)out_size; (void)ws_size;
  const float* x      = (const float*)d_in[0];
  const float* wq     = (const float*)d_in[1];
  const float* wk     = (const float*)d_in[2];
  const float* wv     = (const float*)d_in[3];
  const float* wo     = (const float*)d_in[4];
  const float* prompt = (const float*)d_in[5];
  const float* gate   = (const float*)d_in[6];
  const float* fcos   = (const float*)d_in[7];
  const float* fsin   = (const float*)d_in[8];
  float* out = (float*)d_out;
  char* ws = (char*)d_ws;

  size_t o = 0;
  bf16* xb  = (bf16*)(ws + o); o += (size_t)8388608 * 2;
  bf16* wqb = (bf16*)(ws + o); o += (size_t)16777216 * 2;
  bf16* wkb = (bf16*)(ws + o); o += (size_t)16777216 * 2;
  bf16* wvb = (bf16*)(ws + o); o += (size_t)16777216 * 2;
  bf16* wob = (bf16*)(ws + o); o += (size_t)16777216 * 2;
  bf16* pb  = (bf16*)(ws + o); o += (size_t)40960 * 2;
  bf16* q_ws  = (bf16*)(ws + o); o += (size_t)2048 * 4096 * 2;
  bf16* k_ws  = (bf16*)(ws + o); o += (size_t)2048 * 4096 * 2;
  bf16* v_ws  = (bf16*)(ws + o); o += (size_t)2048 * 4096 * 2;
  bf16* vT_ws = (bf16*)(ws + o); o += (size_t)2048 * 4096 * 2;
  bf16* pk_ws = (bf16*)(ws + o); o += (size_t)40960 * 2;
  bf16* pv_ws = (bf16*)(ws + o); o += (size_t)40960 * 2;
  bf16* attn_ws = v_ws;

  // 1. downcast inputs to bf16
  cvt6<<<dim3(36884), 256, 0, stream>>>(x, wq, wk, wv, wo, prompt,
                                        xb, wqb, wkb, wvb, wob, pb);
  // 2. QKV (+prompt K/V rows): 9 m-tiles x 16 n-tiles per z
  gemm_bt<<<dim3(144, 1, 3), 512, 0, stream>>>(
      xb, pb, wqb, wkb, wvb, q_ws, k_ws, v_ws, pk_ws, pv_ws, 2048, 2058);
  // 3. K-RoPE + V->VT (Q-RoPE fused into flash)
  prep_qkv<<<dim3(2048, 2), 256, 0, stream>>>(k_ws, fcos, fsin, v_ws, vT_ws);
  // 4. flash attention v3d (pair-balanced qb remap)
  flash_attn<<<dim3(16, 64), 256, 0, stream>>>(
      q_ws, k_ws, vT_ws, pk_ws, pv_ws, gate, fcos, fsin, attn_ws);
  // 5. output projection: 256x128 tiles, 256 blocks, f32 out
  gemm_n128<<<dim3(256), 512, 0, stream>>>(attn_ws, wob, out);
}